// Round 1
// baseline (391.153 us; speedup 1.0000x reference)
//
#include <hip/hip_runtime.h>
#include <hip/hip_bf16.h>

#define IN_F 4096
#define OUT_F 4096
#define M_ROWS 8192

#define BM 128
#define BN 128
#define BK 64

typedef __attribute__((ext_vector_type(8))) __bf16 bf16x8;
typedef __attribute__((ext_vector_type(4))) float f32x4;
typedef __attribute__((address_space(1))) const unsigned int GUI;
typedef __attribute__((address_space(3))) unsigned int LUI;

// ---------------------------------------------------------------------------
// Kernel 1: nested dequant of HQQ 4-bit weights -> bf16 [OUT_F][IN_F]
// One thread per 8 weight elements (one int4x2 load, one 16B store).
// ---------------------------------------------------------------------------
__global__ __launch_bounds__(256) void dequant_w_kernel(
    const int* __restrict__ Wq, const int* __restrict__ sq, const int* __restrict__ zq,
    const float* __restrict__ ss, const float* __restrict__ zs,
    const float* __restrict__ sz, const float* __restrict__ zz,
    unsigned short* __restrict__ Wb)
{
    int tid = blockIdx.x * blockDim.x + threadIdx.x;   // 2,097,152 threads
    int g = tid >> 3;            // group id (262144 groups)
    int off = (tid & 7) << 3;    // 0..56 within group of 64

    float scale = ((float)sq[g] - zs[0]) * ss[0];
    float zero  = ((float)zq[g] - zz[0]) * sz[0];

    const int4* p = reinterpret_cast<const int4*>(Wq + ((size_t)g << 6) + off);
    int4 q0 = p[0], q1 = p[1];
    int qs[8] = {q0.x, q0.y, q0.z, q0.w, q1.x, q1.y, q1.z, q1.w};

    unsigned short w[8];
#pragma unroll
    for (int j = 0; j < 8; ++j) {
        __hip_bfloat16 b = __float2bfloat16(((float)qs[j] - zero) * scale);
        w[j] = *reinterpret_cast<unsigned short*>(&b);
    }
    *reinterpret_cast<int4*>(Wb + ((size_t)g << 6) + off) =
        *reinterpret_cast<int4*>(w);
}

// ---------------------------------------------------------------------------
// Kernel 2: x fp32 -> bf16 (one thread per 8 elements)
// ---------------------------------------------------------------------------
__global__ __launch_bounds__(256) void convert_x_kernel(
    const float* __restrict__ x, unsigned short* __restrict__ xb)
{
    size_t tid = (size_t)blockIdx.x * blockDim.x + threadIdx.x;  // 4,194,304 threads
    size_t base = tid << 3;
    const float4* p = reinterpret_cast<const float4*>(x + base);
    float4 f0 = p[0], f1 = p[1];
    float fs[8] = {f0.x, f0.y, f0.z, f0.w, f1.x, f1.y, f1.z, f1.w};
    unsigned short w[8];
#pragma unroll
    for (int j = 0; j < 8; ++j) {
        __hip_bfloat16 b = __float2bfloat16(fs[j]);
        w[j] = *reinterpret_cast<unsigned short*>(&b);
    }
    *reinterpret_cast<int4*>(xb + base) = *reinterpret_cast<int4*>(w);
}

// ---------------------------------------------------------------------------
// Kernel 3: bf16 GEMM, C[M][N] = A[M][K] * B[N][K]^T + bias
// m97 structure: 128x128 tile, BK=64, 4 waves (2x2), each wave 64x64 out,
// mfma_f32_16x16x32_bf16, global_load_lds width=16, single-buffered LDS.
// ---------------------------------------------------------------------------
__global__ __launch_bounds__(256, 3) void gemm_bf16_kernel(
    const unsigned short* __restrict__ A,   // [M][K] bf16
    const unsigned short* __restrict__ B,   // [N][K] bf16 (= W row-major)
    const float* __restrict__ bias,
    float* __restrict__ C, int M, int N, int K)
{
    __shared__ unsigned short As[BM * BK];
    __shared__ unsigned short Bs[BN * BK];

    // Bijective XCD-aware swizzle (nwg = 2048, divisible by 8)
    int nwg = gridDim.x;
    int bid = blockIdx.x;
    int cpx = nwg >> 3;
    int swz = (bid & 7) * cpx + (bid >> 3);
    int nbx = N / BN;            // 32
    int bx = swz % nbx;
    int by = swz / nbx;

    int tid = threadIdx.x;
    int lane = tid & 63;
    int wid = tid >> 6;
    int wr = wid >> 1;           // wave row (0..1)
    int wc = wid & 1;            // wave col (0..1)

    f32x4 acc[4][4] = {};

    // staging: thread t loads 16B; tile row = tid>>3 (+ch*32), col elems = (tid&7)*8
    int r_st = tid >> 3;
    int c_st = (tid & 7) << 3;
    const unsigned short* Ag = A + (size_t)(by * BM + r_st) * K + c_st;
    const unsigned short* Bg = B + (size_t)(bx * BN + r_st) * K + c_st;

    // LDS staging dest: wave-uniform base; HW adds lane*16
    char* AsDst = (char*)As + wid * 1024;
    char* BsDst = (char*)Bs + wid * 1024;

    // LDS read addresses for MFMA fragments
    int lr = lane & 15;
    int kc = (lane >> 4) << 3;   // 0,8,16,24
    const unsigned short* AsRd = As + (size_t)(wr * 64 + lr) * BK + kc;
    const unsigned short* BsRd = Bs + (size_t)(wc * 64 + lr) * BK + kc;

    for (int k0 = 0; k0 < K; k0 += BK) {
#pragma unroll
        for (int ch = 0; ch < 4; ++ch) {
            __builtin_amdgcn_global_load_lds((GUI*)(Ag + (size_t)ch * 32 * K + k0),
                                             (LUI*)(AsDst + ch * 4096), 16, 0, 0);
            __builtin_amdgcn_global_load_lds((GUI*)(Bg + (size_t)ch * 32 * K + k0),
                                             (LUI*)(BsDst + ch * 4096), 16, 0, 0);
        }
        __syncthreads();
#pragma unroll
        for (int kk = 0; kk < BK; kk += 32) {
            bf16x8 a[4], b[4];
#pragma unroll
            for (int m = 0; m < 4; ++m)
                a[m] = *reinterpret_cast<const bf16x8*>(AsRd + m * 16 * BK + kk);
#pragma unroll
            for (int n = 0; n < 4; ++n)
                b[n] = *reinterpret_cast<const bf16x8*>(BsRd + n * 16 * BK + kk);
#pragma unroll
            for (int m = 0; m < 4; ++m)
#pragma unroll
                for (int n = 0; n < 4; ++n)
                    acc[m][n] = __builtin_amdgcn_mfma_f32_16x16x32_bf16(
                        a[m], b[n], acc[m][n], 0, 0, 0);
        }
        __syncthreads();
    }

    // Epilogue: C/D layout for 16x16x32: col = lane&15, row = (lane>>4)*4 + reg
    int row0 = by * BM + wr * 64 + ((lane >> 4) << 2);
    int col0 = bx * BN + wc * 64 + lr;
#pragma unroll
    for (int n = 0; n < 4; ++n) {
        int col = col0 + n * 16;
        float bv = bias[col];
#pragma unroll
        for (int m = 0; m < 4; ++m) {
#pragma unroll
            for (int r = 0; r < 4; ++r) {
                int row = row0 + m * 16 + r;
                C[(size_t)row * N + col] = acc[m][n][r] + bv;
            }
        }
    }
}

// ---------------------------------------------------------------------------
extern "C" void kernel_launch(void* const* d_in, const int* in_sizes, int n_in,
                              void* d_out, int out_size, void* d_ws, size_t ws_size,
                              hipStream_t stream) {
    const float* x      = (const float*)d_in[0];
    const int*   Wq     = (const int*)d_in[1];
    const int*   sq     = (const int*)d_in[2];
    const int*   zq     = (const int*)d_in[3];
    const float* ss     = (const float*)d_in[4];
    const float* zs     = (const float*)d_in[5];
    const float* sz     = (const float*)d_in[6];
    const float* zz     = (const float*)d_in[7];
    const float* bias   = (const float*)d_in[8];
    float* out = (float*)d_out;

    // workspace: x_bf16 [8192*4096] then W_bf16 [4096*4096]
    unsigned short* xb = (unsigned short*)d_ws;
    unsigned short* Wb = (unsigned short*)((char*)d_ws + (size_t)M_ROWS * IN_F * 2);

    // dequant W: 262144 groups * 8 threads = 2,097,152 threads
    dequant_w_kernel<<<8192, 256, 0, stream>>>(Wq, sq, zq, ss, zs, sz, zz, Wb);
    // convert x: 33,554,432 elems / 8 = 4,194,304 threads
    convert_x_kernel<<<16384, 256, 0, stream>>>(x, xb);
    // GEMM: (8192/128) * (4096/128) = 2048 blocks
    gemm_bf16_kernel<<<2048, 256, 0, stream>>>(xb, Wb, bias, out,
                                               M_ROWS, OUT_F, IN_F);
}

// Round 2
// 322.389 us; speedup vs baseline: 1.2133x; 1.2133x over previous
//
#include <hip/hip_runtime.h>
#include <hip/hip_bf16.h>

#define IN_F 4096
#define OUT_F 4096
#define M_ROWS 8192

#define BM 256
#define BN 256
#define KSLICE 32              // k-elems per slice
#define NSLICES 128            // IN_F / KSLICE

typedef __attribute__((ext_vector_type(8))) __bf16 bf16x8;
typedef __attribute__((ext_vector_type(4))) float f32x4;
typedef __attribute__((address_space(1))) const unsigned int GUI;
typedef __attribute__((address_space(3))) unsigned int LUI;

// ---------------------------------------------------------------------------
// Kernel 1: nested dequant of HQQ 4-bit weights -> bf16 [OUT_F][IN_F]
// ---------------------------------------------------------------------------
__global__ __launch_bounds__(256) void dequant_w_kernel(
    const int* __restrict__ Wq, const int* __restrict__ sq, const int* __restrict__ zq,
    const float* __restrict__ ss, const float* __restrict__ zs,
    const float* __restrict__ sz, const float* __restrict__ zz,
    unsigned short* __restrict__ Wb)
{
    int tid = blockIdx.x * blockDim.x + threadIdx.x;   // 2,097,152 threads
    int g = tid >> 3;
    int off = (tid & 7) << 3;

    float scale = ((float)sq[g] - zs[0]) * ss[0];
    float zero  = ((float)zq[g] - zz[0]) * sz[0];

    const int4* p = reinterpret_cast<const int4*>(Wq + ((size_t)g << 6) + off);
    int4 q0 = p[0], q1 = p[1];
    int qs[8] = {q0.x, q0.y, q0.z, q0.w, q1.x, q1.y, q1.z, q1.w};

    unsigned short w[8];
#pragma unroll
    for (int j = 0; j < 8; ++j) {
        __hip_bfloat16 b = __float2bfloat16(((float)qs[j] - zero) * scale);
        w[j] = *reinterpret_cast<unsigned short*>(&b);
    }
    *reinterpret_cast<int4*>(Wb + ((size_t)g << 6) + off) =
        *reinterpret_cast<int4*>(w);
}

// ---------------------------------------------------------------------------
// Kernel 2: x fp32 -> bf16
// ---------------------------------------------------------------------------
__global__ __launch_bounds__(256) void convert_x_kernel(
    const float* __restrict__ x, unsigned short* __restrict__ xb)
{
    size_t tid = (size_t)blockIdx.x * blockDim.x + threadIdx.x;
    size_t base = tid << 3;
    const float4* p = reinterpret_cast<const float4*>(x + base);
    float4 f0 = p[0], f1 = p[1];
    float fs[8] = {f0.x, f0.y, f0.z, f0.w, f1.x, f1.y, f1.z, f1.w};
    unsigned short w[8];
#pragma unroll
    for (int j = 0; j < 8; ++j) {
        __hip_bfloat16 b = __float2bfloat16(fs[j]);
        w[j] = *reinterpret_cast<unsigned short*>(&b);
    }
    *reinterpret_cast<int4*>(xb + base) = *reinterpret_cast<int4*>(w);
}

// ---------------------------------------------------------------------------
// Kernel 3: 256x256-tile bf16 GEMM, k-slice software pipeline.
//   C[M][N] = A[M][K] * B[N][K]^T + bias
// 8 waves (2M x 4N), wave tile 128x64. LDS: ring of 4 k-slices per operand
// ([4][256][32] bf16 each = 64 KiB; 128 KiB total).
// T2 swizzle: 16B-slot ^= (row>>1)&3 (2-way max on ds_read_b128).
// T3/T4: prefetch distance 3 slices, vmcnt(8) once per slice (never 0 in loop).
// T5: setprio around MFMA clusters. T1: bijective XCD swizzle.
// ---------------------------------------------------------------------------
__global__ __launch_bounds__(512, 2) void gemm_bf16_kernel(
    const unsigned short* __restrict__ A,   // [M][K] bf16
    const unsigned short* __restrict__ B,   // [N][K] bf16
    const float* __restrict__ bias,
    float* __restrict__ C)
{
    __shared__ __align__(16) unsigned short As[4][BM * KSLICE];
    __shared__ __align__(16) unsigned short Bs[4][BM * KSLICE];

    const int K = IN_F;

    // XCD-aware bijective swizzle: 512 blocks, 8 XCDs, 64 per XCD
    int bid = blockIdx.x;
    int swz = (bid & 7) * 64 + (bid >> 3);
    int bx = swz & 15;           // 16 N-tiles
    int by = swz >> 4;           // 32 M-tiles

    int tid = threadIdx.x;
    int lane = tid & 63;
    int wid = tid >> 6;
    int wr = wid >> 2;           // 0..1  (M)
    int wc = wid & 3;            // 0..3  (N)

    // ---- staging: one slice chunk = 256 rows x 32 elems (64B rows), 16 KiB.
    // 512 threads x 2 loads x 16B. Load i: LDS byte p=(i*512+tid)*16,
    // row=(i*512+tid)>>2, slot=tid&3. Source slot pre-swizzled: ^ (row>>1)&3.
    int srow0 = tid >> 2;                 // 0..127
    int srow1 = srow0 + 128;
    int sslot = tid & 3;
    int ss0 = sslot ^ ((srow0 >> 1) & 3);
    int ss1 = sslot ^ ((srow1 >> 1) & 3);
    const unsigned short* Asrc0 = A + (size_t)(by * BM + srow0) * K + ss0 * 8;
    const unsigned short* Asrc1 = A + (size_t)(by * BM + srow1) * K + ss1 * 8;
    const unsigned short* Bsrc0 = B + (size_t)(bx * BN + srow0) * K + ss0 * 8;
    const unsigned short* Bsrc1 = B + (size_t)(bx * BN + srow1) * K + ss1 * 8;

    // wave-uniform LDS dest bases (HW adds lane*16)
    char* AsW = (char*)As + wid * 1024;
    char* BsW = (char*)Bs + wid * 1024;

#define STAGE_A(s) do { int _t = (s) & 3;                                        \
    __builtin_amdgcn_global_load_lds((GUI*)(Asrc0 + (size_t)(s) * KSLICE),       \
        (LUI*)(AsW + _t * 16384), 16, 0, 0);                                     \
    __builtin_amdgcn_global_load_lds((GUI*)(Asrc1 + (size_t)(s) * KSLICE),       \
        (LUI*)(AsW + _t * 16384 + 8192), 16, 0, 0); } while (0)
#define STAGE_B(s) do { int _t = (s) & 3;                                        \
    __builtin_amdgcn_global_load_lds((GUI*)(Bsrc0 + (size_t)(s) * KSLICE),       \
        (LUI*)(BsW + _t * 16384), 16, 0, 0);                                     \
    __builtin_amdgcn_global_load_lds((GUI*)(Bsrc1 + (size_t)(s) * KSLICE),       \
        (LUI*)(BsW + _t * 16384 + 8192), 16, 0, 0); } while (0)

    // ---- fragment read addressing. Logical: lane reads row=(base+m*16+lr),
    // 8 k-elems at slot=lane>>4. Swizzle term (lr>>1)&3 is invariant in m/n
    // (m*16 rows == 8 slots-pairs, mod-4 free), so frag = base + m*1024 bytes.
    int lr = lane & 15;
    int lslot = lane >> 4;
    int srd = lslot ^ ((lr >> 1) & 3);
    int aoff = (wr * 128 + lr) * 64 + srd * 16;   // bytes within A slot buf
    int boff = (wc * 64 + lr) * 64 + srd * 16;    // bytes within B slot buf

    f32x4 acc[8][4] = {};

    // prologue: slices 0,1,2 in flight (12 loads/thread)
    STAGE_A(0); STAGE_B(0); STAGE_A(1); STAGE_B(1); STAGE_A(2); STAGE_B(2);

    // main loop: slices 0 .. 125. At slice s, outstanding after B(s) is
    // exactly A/B(s+1), A/B(s+2) = 8 loads -> vmcnt(8) guarantees slice s
    // resident; barrier makes it workgroup-wide before any ring overwrite.
    for (int s = 0; s < NSLICES - 2; ++s) {
        int slt = s & 3;
        asm volatile("s_waitcnt vmcnt(8)" ::: "memory");
        __builtin_amdgcn_s_barrier();
        asm volatile("" ::: "memory");

        const char* Ap = (const char*)As + slt * 16384 + aoff;
        const char* Bp = (const char*)Bs + slt * 16384 + boff;
        bf16x8 a[4], b[4];
#pragma unroll
        for (int n = 0; n < 4; ++n) b[n] = *(const bf16x8*)(Bp + n * 1024);
#pragma unroll
        for (int m = 0; m < 4; ++m) a[m] = *(const bf16x8*)(Ap + m * 1024);

        bool st = (s + 3 < NSLICES);
        if (st) STAGE_A(s + 3);

        __builtin_amdgcn_s_setprio(1);
#pragma unroll
        for (int m = 0; m < 4; ++m)
#pragma unroll
            for (int n = 0; n < 4; ++n)
                acc[m][n] = __builtin_amdgcn_mfma_f32_16x16x32_bf16(
                    a[m], b[n], acc[m][n], 0, 0, 0);
        __builtin_amdgcn_s_setprio(0);

        // phase B: m-frags 4..7, B-frags reused from registers
#pragma unroll
        for (int m = 0; m < 4; ++m) a[m] = *(const bf16x8*)(Ap + (4 + m) * 1024);
        if (st) STAGE_B(s + 3);

        __builtin_amdgcn_s_setprio(1);
#pragma unroll
        for (int m = 0; m < 4; ++m)
#pragma unroll
            for (int n = 0; n < 4; ++n)
                acc[4 + m][n] = __builtin_amdgcn_mfma_f32_16x16x32_bf16(
                    a[m], b[n], acc[4 + m][n], 0, 0, 0);
        __builtin_amdgcn_s_setprio(0);
    }

    // epilogue: slices 126,127 — drain once, no stages pending afterwards
    asm volatile("s_waitcnt vmcnt(0)" ::: "memory");
    __builtin_amdgcn_s_barrier();
    asm volatile("" ::: "memory");
#pragma unroll
    for (int e = 0; e < 2; ++e) {
        int slt = (NSLICES - 2 + e) & 3;
        const char* Ap = (const char*)As + slt * 16384 + aoff;
        const char* Bp = (const char*)Bs + slt * 16384 + boff;
        bf16x8 b[4];
#pragma unroll
        for (int n = 0; n < 4; ++n) b[n] = *(const bf16x8*)(Bp + n * 1024);
#pragma unroll
        for (int m = 0; m < 8; ++m) {
            bf16x8 a = *(const bf16x8*)(Ap + m * 1024);
#pragma unroll
            for (int n = 0; n < 4; ++n)
                acc[m][n] = __builtin_amdgcn_mfma_f32_16x16x32_bf16(
                    a, b[n], acc[m][n], 0, 0, 0);
        }
    }

    // C write: 16x16x32 C/D layout col=lane&15, row=(lane>>4)*4+r
    int row0 = by * BM + wr * 128 + (lane >> 4) * 4;
    int col0 = bx * BN + wc * 64 + (lane & 15);
#pragma unroll
    for (int n = 0; n < 4; ++n) {
        int col = col0 + n * 16;
        float bv = bias[col];
#pragma unroll
        for (int m = 0; m < 8; ++m) {
#pragma unroll
            for (int r = 0; r < 4; ++r) {
                int row = row0 + m * 16 + r;
                C[(size_t)row * OUT_F + col] = acc[m][n][r] + bv;
            }
        }
    }
#undef STAGE_A
#undef STAGE_B
}

// ---------------------------------------------------------------------------
extern "C" void kernel_launch(void* const* d_in, const int* in_sizes, int n_in,
                              void* d_out, int out_size, void* d_ws, size_t ws_size,
                              hipStream_t stream) {
    const float* x      = (const float*)d_in[0];
    const int*   Wq     = (const int*)d_in[1];
    const int*   sq     = (const int*)d_in[2];
    const int*   zq     = (const int*)d_in[3];
    const float* ss     = (const float*)d_in[4];
    const float* zs     = (const float*)d_in[5];
    const float* sz     = (const float*)d_in[6];
    const float* zz     = (const float*)d_in[7];
    const float* bias   = (const float*)d_in[8];
    float* out = (float*)d_out;

    unsigned short* xb = (unsigned short*)d_ws;
    unsigned short* Wb = (unsigned short*)((char*)d_ws + (size_t)M_ROWS * IN_F * 2);

    dequant_w_kernel<<<8192, 256, 0, stream>>>(Wq, sq, zq, ss, zs, sz, zz, Wb);
    convert_x_kernel<<<16384, 256, 0, stream>>>(x, xb);
    // (8192/256) * (4096/256) = 32*16 = 512 blocks, 512 threads
    gemm_bf16_kernel<<<512, 512, 0, stream>>>(xb, Wb, bias, out);
}

// Round 3
// 268.222 us; speedup vs baseline: 1.4583x; 1.2020x over previous
//
#include <hip/hip_runtime.h>
#include <hip/hip_bf16.h>

#define IN_F 4096
#define OUT_F 4096
#define M_ROWS 8192

#define BM 256
#define BN 256
#define BK 64
#define NT 64                  // IN_F / BK K-tiles

typedef __attribute__((ext_vector_type(8))) __bf16 bf16x8;
typedef __attribute__((ext_vector_type(4))) float f32x4;
typedef __attribute__((address_space(1))) const unsigned int GUI;
typedef __attribute__((address_space(3))) unsigned int LUI;

// ---------------------------------------------------------------------------
// Kernel 1: nested dequant of HQQ 4-bit weights -> bf16 [OUT_F][IN_F]
// ---------------------------------------------------------------------------
__global__ __launch_bounds__(256) void dequant_w_kernel(
    const int* __restrict__ Wq, const int* __restrict__ sq, const int* __restrict__ zq,
    const float* __restrict__ ss, const float* __restrict__ zs,
    const float* __restrict__ sz, const float* __restrict__ zz,
    unsigned short* __restrict__ Wb)
{
    int tid = blockIdx.x * blockDim.x + threadIdx.x;
    int g = tid >> 3;
    int off = (tid & 7) << 3;

    float scale = ((float)sq[g] - zs[0]) * ss[0];
    float zero  = ((float)zq[g] - zz[0]) * sz[0];

    const int4* p = reinterpret_cast<const int4*>(Wq + ((size_t)g << 6) + off);
    int4 q0 = p[0], q1 = p[1];
    int qs[8] = {q0.x, q0.y, q0.z, q0.w, q1.x, q1.y, q1.z, q1.w};

    unsigned short w[8];
#pragma unroll
    for (int j = 0; j < 8; ++j) {
        __hip_bfloat16 b = __float2bfloat16(((float)qs[j] - zero) * scale);
        w[j] = *reinterpret_cast<unsigned short*>(&b);
    }
    *reinterpret_cast<int4*>(Wb + ((size_t)g << 6) + off) =
        *reinterpret_cast<int4*>(w);
}

// ---------------------------------------------------------------------------
// Kernel 2: x fp32 -> bf16
// ---------------------------------------------------------------------------
__global__ __launch_bounds__(256) void convert_x_kernel(
    const float* __restrict__ x, unsigned short* __restrict__ xb)
{
    size_t tid = (size_t)blockIdx.x * blockDim.x + threadIdx.x;
    size_t base = tid << 3;
    const float4* p = reinterpret_cast<const float4*>(x + base);
    float4 f0 = p[0], f1 = p[1];
    float fs[8] = {f0.x, f0.y, f0.z, f0.w, f1.x, f1.y, f1.z, f1.w};
    unsigned short w[8];
#pragma unroll
    for (int j = 0; j < 8; ++j) {
        __hip_bfloat16 b = __float2bfloat16(fs[j]);
        w[j] = *reinterpret_cast<unsigned short*>(&b);
    }
    *reinterpret_cast<int4*>(xb + base) = *reinterpret_cast<int4*>(w);
}

// ---------------------------------------------------------------------------
// Kernel 3: 256x256 8-phase bf16 GEMM (m201 template), C = A * B^T + bias.
// 8 waves (2M x 4N), wave tile 128x64, BK=64, double-buffered LDS (128 KiB).
// Per K-tile: 4 phases (C-quadrants), each {ds_read subtile | stage 1
// half-tile | barrier | lgkmcnt(0) | setprio(1) | 16 MFMA | setprio(0) |
// barrier}. vmcnt(4) once per K-tile at phase 4. Swizzle: slot ^= row&7
// (128B rows, 8x16B slots), pre-swizzled global source + swizzled read.
// ---------------------------------------------------------------------------
__global__ __launch_bounds__(512, 2) void gemm_bf16_kernel(
    const unsigned short* __restrict__ A,   // [M][K] bf16
    const unsigned short* __restrict__ B,   // [N][K] bf16
    const float* __restrict__ bias,
    float* __restrict__ C)
{
    // LDS: A bufs at [0, 65536), B bufs at [65536, 131072). Each buf 32 KiB =
    // 2 halves x 128 rows x 128 B. byte(row, slot) = row*128 + (slot^(row&7))*16.
    __shared__ __align__(16) char lds[131072];

    const int K = IN_F;

    // T1: bijective XCD swizzle (512 blocks, 8 XCDs)
    int bid = blockIdx.x;
    int swz = (bid & 7) * 64 + (bid >> 3);
    int bx = swz & 15;           // 16 N-tiles
    int by = swz >> 4;           // 32 M-tiles

    int tid = threadIdx.x;
    int lane = tid & 63;
    int wid = tid >> 6;
    int wr = wid >> 2;           // 0..1 (M)
    int wc = wid & 3;            // 0..3 (N)

    // ---- staging addressing (linear LDS dest; pre-swizzled global source)
    // thread t, load i of a half-tile: LDS byte (i*512+t)*16 ->
    // row_local = i*64 + (t>>3), lin slot = t&7, src slot = (t&7)^((t>>3)&7)
    int roff = tid >> 3;                                  // 0..63
    int soff = (((tid & 7) ^ ((tid >> 3) & 7)) << 3);     // src k-elem offset
    const unsigned short* srcA = A + (size_t)(by * BM + roff) * K + soff;
    const unsigned short* srcB = B + (size_t)(bx * BN + roff) * K + soff;

#define STAGE_A(kt, h, D2) do {                                               \
    __builtin_amdgcn_global_load_lds(                                         \
        (GUI*)(srcA + (size_t)((h)*128) * IN_F + (size_t)(kt) * BK),          \
        (LUI*)(lds + (D2)*32768 + (h)*16384 + wid*1024), 16, 0, 0);           \
    __builtin_amdgcn_global_load_lds(                                         \
        (GUI*)(srcA + (size_t)((h)*128 + 64) * IN_F + (size_t)(kt) * BK),     \
        (LUI*)(lds + (D2)*32768 + (h)*16384 + 8192 + wid*1024), 16, 0, 0);    \
    } while (0)
#define STAGE_B(kt, h, D2) do {                                               \
    __builtin_amdgcn_global_load_lds(                                         \
        (GUI*)(srcB + (size_t)((h)*128) * IN_F + (size_t)(kt) * BK),          \
        (LUI*)(lds + 65536 + (D2)*32768 + (h)*16384 + wid*1024), 16, 0, 0);   \
    __builtin_amdgcn_global_load_lds(                                         \
        (GUI*)(srcB + (size_t)((h)*128 + 64) * IN_F + (size_t)(kt) * BK),     \
        (LUI*)(lds + 65536 + (D2)*32768 + (h)*16384 + 8192 + wid*1024),       \
        16, 0, 0);                                                            \
    } while (0)

    // ---- fragment read addressing (swizzled)
    // frag(row, kslot kq, kstep ks): byte = row*128 + ((4*ks+kq)^(row&7))*16
    //  = row*128 + (kq^(lr&3))*16 + (ks^((lr>>2)&1))*64   [row&7 == lr&7]
    int lr = lane & 15;
    int kq = lane >> 4;                       // 0..3
    int cslot = (kq ^ (lr & 3)) << 4;
    int offk0 = ((lr >> 2) & 1) << 6;
    int offk1 = 64 - offk0;
    int aRd = (wr * 128 + lr) * 128 + cslot;  // + h*8192 + m*2048 + offk
    int bRd = (wc * 64 + lr) * 128 + cslot;   // + c*4096 + n*2048 + offk

#define RDA(D2, h, m, ks) (*(const bf16x8*)(lds + (D2)*32768 + aRd +          \
        (h)*8192 + (m)*2048 + ((ks) ? offk1 : offk0)))
#define RDB(D2, c, n, ks) (*(const bf16x8*)(lds + 65536 + (D2)*32768 + bRd +  \
        (c)*4096 + (n)*2048 + ((ks) ? offk1 : offk0)))

    f32x4 acc[8][4] = {};
    bf16x8 a[4][2], b0[2][2], b1[2][2];

#define PRE_MFMA                                                              \
    __builtin_amdgcn_s_barrier();                                             \
    asm volatile("s_waitcnt lgkmcnt(0)" ::: "memory");                        \
    __builtin_amdgcn_s_setprio(1);
#define POST_MFMA                                                             \
    __builtin_amdgcn_s_setprio(0);                                            \
    __builtin_amdgcn_s_barrier();

    // One K-tile = 4 phases. Stage ledger (per K-tile k, buffer D=k&1):
    //   P0: stage B1(k+1)->D^1   (B1(k-1) last read at P1(k-1): safe)
    //   P1: stage A1(k+1)->D^1   (A1(k-1) last read at P2(k-1): safe)
    //   P2: stage B0(k+2)->D     (B0(k)   last read at P1(k):   safe)
    //   P3: stage A0(k+2)->D     (A0(k)   last read at P2(k):   safe)
    //   P3: vmcnt(4)+barrier -> covers A1(k+1) and older, i.e. ALL of k+1
    //       (only B0(k+2), A0(k+2) = 4 loads may remain in flight).
#define KTILE(kt, D, S01, S23, VM) do {                                       \
    /* ---- P0: quadrant (h=0, c=0) ---- */                                   \
    _Pragma("unroll") for (int m = 0; m < 4; ++m) {                           \
        a[m][0] = RDA(D, 0, m, 0); a[m][1] = RDA(D, 0, m, 1); }               \
    _Pragma("unroll") for (int n = 0; n < 2; ++n) {                           \
        b0[n][0] = RDB(D, 0, n, 0); b0[n][1] = RDB(D, 0, n, 1); }             \
    if (S01) STAGE_B((kt) + 1, 1, (D) ^ 1);                                   \
    PRE_MFMA                                                                  \
    _Pragma("unroll") for (int m = 0; m < 4; ++m)                             \
    _Pragma("unroll") for (int n = 0; n < 2; ++n)                             \
    _Pragma("unroll") for (int ks = 0; ks < 2; ++ks)                          \
        acc[m][n] = __builtin_amdgcn_mfma_f32_16x16x32_bf16(                  \
            a[m][ks], b0[n][ks], acc[m][n], 0, 0, 0);                         \
    POST_MFMA                                                                 \
    /* ---- P1: quadrant (h=0, c=1) ---- */                                   \
    _Pragma("unroll") for (int n = 0; n < 2; ++n) {                           \
        b1[n][0] = RDB(D, 1, n, 0); b1[n][1] = RDB(D, 1, n, 1); }             \
    if (S01) STAGE_A((kt) + 1, 1, (D) ^ 1);                                   \
    PRE_MFMA                                                                  \
    _Pragma("unroll") for (int m = 0; m < 4; ++m)                             \
    _Pragma("unroll") for (int n = 0; n < 2; ++n)                             \
    _Pragma("unroll") for (int ks = 0; ks < 2; ++ks)                          \
        acc[m][2 + n] = __builtin_amdgcn_mfma_f32_16x16x32_bf16(              \
            a[m][ks], b1[n][ks], acc[m][2 + n], 0, 0, 0);                     \
    POST_MFMA                                                                 \
    /* ---- P2: quadrant (h=1, c=0) ---- */                                   \
    _Pragma("unroll") for (int m = 0; m < 4; ++m) {                           \
        a[m][0] = RDA(D, 1, m, 0); a[m][1] = RDA(D, 1, m, 1); }               \
    if (S23) STAGE_B((kt) + 2, 0, D);                                         \
    PRE_MFMA                                                                  \
    _Pragma("unroll") for (int m = 0; m < 4; ++m)                             \
    _Pragma("unroll") for (int n = 0; n < 2; ++n)                             \
    _Pragma("unroll") for (int ks = 0; ks < 2; ++ks)                          \
        acc[4 + m][n] = __builtin_amdgcn_mfma_f32_16x16x32_bf16(              \
            a[m][ks], b0[n][ks], acc[4 + m][n], 0, 0, 0);                     \
    POST_MFMA                                                                 \
    /* ---- P3: quadrant (h=1, c=1) ---- */                                   \
    if (S23) STAGE_A((kt) + 2, 0, D);                                         \
    if ((VM) == 4) asm volatile("s_waitcnt vmcnt(4)" ::: "memory");           \
    else if ((VM) == 0) asm volatile("s_waitcnt vmcnt(0)" ::: "memory");      \
    PRE_MFMA                                                                  \
    _Pragma("unroll") for (int m = 0; m < 4; ++m)                             \
    _Pragma("unroll") for (int n = 0; n < 2; ++n)                             \
    _Pragma("unroll") for (int ks = 0; ks < 2; ++ks)                          \
        acc[4 + m][2 + n] = __builtin_amdgcn_mfma_f32_16x16x32_bf16(          \
            a[m][ks], b1[n][ks], acc[4 + m][2 + n], 0, 0, 0);                 \
    POST_MFMA                                                                 \
    } while (0)

    // prologue: K-tile 0 fully + B0/A0 of K-tile 1 (12 loads/thread);
    // vmcnt(4) leaves exactly B0(1), A0(1) in flight.
    STAGE_B(0, 0, 0); STAGE_A(0, 0, 0);
    STAGE_B(0, 1, 0); STAGE_A(0, 1, 0);
    STAGE_B(1, 0, 1); STAGE_A(1, 0, 1);
    asm volatile("s_waitcnt vmcnt(4)" ::: "memory");
    __builtin_amdgcn_s_barrier();

    for (int t = 0; t < (NT - 2) / 2; ++t) {   // k = 0 .. 61
        int k0 = 2 * t;
        KTILE(k0, 0, 1, 1, 4);
        KTILE(k0 + 1, 1, 1, 1, 4);
    }
    KTILE(NT - 2, 0, 1, 0, 0);                 // k = 62: stage B1/A1(63), drain
    KTILE(NT - 1, 1, 0, 0, -1);                // k = 63: compute only

    // ---- epilogue: C/D layout col=lane&15, row=(lane>>4)*4+r
    int row0 = by * BM + wr * 128 + (lane >> 4) * 4;
    int col0 = bx * BN + wc * 64 + lr;
#pragma unroll
    for (int c = 0; c < 2; ++c)
#pragma unroll
    for (int n = 0; n < 2; ++n) {
        int col = col0 + c * 32 + n * 16;
        float bv = bias[col];
#pragma unroll
        for (int h = 0; h < 2; ++h)
#pragma unroll
        for (int m = 0; m < 4; ++m)
#pragma unroll
        for (int r = 0; r < 4; ++r) {
            int row = row0 + h * 64 + m * 16 + r;
            C[(size_t)row * OUT_F + col] = acc[h * 4 + m][c * 2 + n][r] + bv;
        }
    }
#undef KTILE
#undef PRE_MFMA
#undef POST_MFMA
#undef RDA
#undef RDB
#undef STAGE_A
#undef STAGE_B
}

// ---------------------------------------------------------------------------
extern "C" void kernel_launch(void* const* d_in, const int* in_sizes, int n_in,
                              void* d_out, int out_size, void* d_ws, size_t ws_size,
                              hipStream_t stream) {
    const float* x      = (const float*)d_in[0];
    const int*   Wq     = (const int*)d_in[1];
    const int*   sq     = (const int*)d_in[2];
    const int*   zq     = (const int*)d_in[3];
    const float* ss     = (const float*)d_in[4];
    const float* zs     = (const float*)d_in[5];
    const float* sz     = (const float*)d_in[6];
    const float* zz     = (const float*)d_in[7];
    const float* bias   = (const float*)d_in[8];
    float* out = (float*)d_out;

    unsigned short* xb = (unsigned short*)d_ws;
    unsigned short* Wb = (unsigned short*)((char*)d_ws + (size_t)M_ROWS * IN_F * 2);

    dequant_w_kernel<<<8192, 256, 0, stream>>>(Wq, sq, zq, ss, zs, sz, zz, Wb);
    convert_x_kernel<<<16384, 256, 0, stream>>>(x, xb);
    // (8192/256) * (4096/256) = 512 blocks, 512 threads
    gemm_bf16_kernel<<<512, 512, 0, stream>>>(xb, Wb, bias, out);
}

// Round 4
// 258.867 us; speedup vs baseline: 1.5110x; 1.0361x over previous
//
#include <hip/hip_runtime.h>
#include <hip/hip_bf16.h>

#define IN_F 4096
#define OUT_F 4096
#define M_ROWS 8192

#define BM 256
#define BN 256
#define BK 64
#define NT 64                  // IN_F / BK K-tiles

typedef __attribute__((ext_vector_type(8))) __bf16 bf16x8;
typedef __attribute__((ext_vector_type(4))) float f32x4;
typedef __attribute__((address_space(1))) const unsigned int GUI;
typedef __attribute__((address_space(3))) unsigned int LUI;

// ---------------------------------------------------------------------------
// Kernel 1: nested dequant of HQQ 4-bit weights -> bf16 [OUT_F][IN_F]
// ---------------------------------------------------------------------------
__global__ __launch_bounds__(256) void dequant_w_kernel(
    const int* __restrict__ Wq, const int* __restrict__ sq, const int* __restrict__ zq,
    const float* __restrict__ ss, const float* __restrict__ zs,
    const float* __restrict__ sz, const float* __restrict__ zz,
    unsigned short* __restrict__ Wb)
{
    int tid = blockIdx.x * blockDim.x + threadIdx.x;
    int g = tid >> 3;
    int off = (tid & 7) << 3;

    float scale = ((float)sq[g] - zs[0]) * ss[0];
    float zero  = ((float)zq[g] - zz[0]) * sz[0];

    const int4* p = reinterpret_cast<const int4*>(Wq + ((size_t)g << 6) + off);
    int4 q0 = p[0], q1 = p[1];
    int qs[8] = {q0.x, q0.y, q0.z, q0.w, q1.x, q1.y, q1.z, q1.w};

    unsigned short w[8];
#pragma unroll
    for (int j = 0; j < 8; ++j) {
        __hip_bfloat16 b = __float2bfloat16(((float)qs[j] - zero) * scale);
        w[j] = *reinterpret_cast<unsigned short*>(&b);
    }
    *reinterpret_cast<int4*>(Wb + ((size_t)g << 6) + off) =
        *reinterpret_cast<int4*>(w);
}

// ---------------------------------------------------------------------------
// Kernel 2: x fp32 -> bf16
// ---------------------------------------------------------------------------
__global__ __launch_bounds__(256) void convert_x_kernel(
    const float* __restrict__ x, unsigned short* __restrict__ xb)
{
    size_t tid = (size_t)blockIdx.x * blockDim.x + threadIdx.x;
    size_t base = tid << 3;
    const float4* p = reinterpret_cast<const float4*>(x + base);
    float4 f0 = p[0], f1 = p[1];
    float fs[8] = {f0.x, f0.y, f0.z, f0.w, f1.x, f1.y, f1.z, f1.w};
    unsigned short w[8];
#pragma unroll
    for (int j = 0; j < 8; ++j) {
        __hip_bfloat16 b = __float2bfloat16(fs[j]);
        w[j] = *reinterpret_cast<unsigned short*>(&b);
    }
    *reinterpret_cast<int4*>(xb + base) = *reinterpret_cast<int4*>(w);
}

// ---------------------------------------------------------------------------
// Kernel 3: 256x256 bf16 GEMM, 1-barrier-per-phase rotated schedule.
//   C[M][N] = A[M][K] * B[N][K]^T + bias
// 8 waves (2M x 4N), wave tile 128x64, BK=64, double-buffered LDS (128 KiB).
// Per K-tile: 4 phases {BAR; [P0 only: opening 12 ds_reads]; lgkmcnt(0);
// setprio(1); 16 MFMA; setprio(0); tail: next-phase ds_reads + 1 stage}.
// Tail reads hide under the SIMD-partner wave's MFMA window.
// vmcnt(4) once per K-tile (P3 tail), never 0 in main loop.
// Hazard ledger (frame: tile k, buffer D=k&1):
//   P0t: stage B1(k+1)->D^1  (b1(k-1) reads done by BAR@P2top(k-1))
//   P1t: stage A1(k+1)->D^1  (a1(k-1) reads done by BAR@P3top(k-1))
//   P2t: stage B0(k+2)->D    (b0(k) reads done by BAR@P1top(k))
//   P3t: stage A0(k+2)->D    (a0(k) reads done by BAR@P1top(k))
//   P3t: vmcnt(4) leaves {B0,A0}(k+2) pending; ensures all of k+1 resident;
//        BAR@P0top(k+1) publishes cross-wave before the opening reads.
// ---------------------------------------------------------------------------
__global__ __launch_bounds__(512, 2) void gemm_bf16_kernel(
    const unsigned short* __restrict__ A,   // [M][K] bf16
    const unsigned short* __restrict__ B,   // [N][K] bf16
    const float* __restrict__ bias,
    float* __restrict__ C)
{
    // LDS: A bufs [0,64K), B bufs [64K,128K). Buf = 2 halves x 128 rows x 128B.
    // byte(row, slot) = row*128 + (slot^(row&7))*16.
    __shared__ __align__(16) char lds[131072];

    const int K = IN_F;

    // T1: bijective XCD swizzle (512 blocks, 8 XCDs)
    int bid = blockIdx.x;
    int swz = (bid & 7) * 64 + (bid >> 3);
    int bx = swz & 15;           // 16 N-tiles
    int by = swz >> 4;           // 32 M-tiles

    int tid = threadIdx.x;
    int lane = tid & 63;
    int wid = tid >> 6;
    int wr = wid >> 2;           // 0..1 (M)
    int wc = wid & 3;            // 0..3 (N)

    // staging addressing (linear LDS dest; pre-swizzled global source)
    int roff = tid >> 3;                                  // 0..63
    int soff = (((tid & 7) ^ ((tid >> 3) & 7)) << 3);     // src k-elem offset
    const unsigned short* srcA = A + (size_t)(by * BM + roff) * K + soff;
    const unsigned short* srcB = B + (size_t)(bx * BN + roff) * K + soff;

#define STAGE_A(kt, h, D2) do {                                               \
    __builtin_amdgcn_global_load_lds(                                         \
        (GUI*)(srcA + (size_t)((h)*128) * IN_F + (size_t)(kt) * BK),          \
        (LUI*)(lds + (D2)*32768 + (h)*16384 + wid*1024), 16, 0, 0);           \
    __builtin_amdgcn_global_load_lds(                                         \
        (GUI*)(srcA + (size_t)((h)*128 + 64) * IN_F + (size_t)(kt) * BK),     \
        (LUI*)(lds + (D2)*32768 + (h)*16384 + 8192 + wid*1024), 16, 0, 0);    \
    } while (0)
#define STAGE_B(kt, h, D2) do {                                               \
    __builtin_amdgcn_global_load_lds(                                         \
        (GUI*)(srcB + (size_t)((h)*128) * IN_F + (size_t)(kt) * BK),          \
        (LUI*)(lds + 65536 + (D2)*32768 + (h)*16384 + wid*1024), 16, 0, 0);   \
    __builtin_amdgcn_global_load_lds(                                         \
        (GUI*)(srcB + (size_t)((h)*128 + 64) * IN_F + (size_t)(kt) * BK),     \
        (LUI*)(lds + 65536 + (D2)*32768 + (h)*16384 + 8192 + wid*1024),       \
        16, 0, 0);                                                            \
    } while (0)

    // fragment read addressing (swizzled)
    int lr = lane & 15;
    int kq = lane >> 4;                       // 0..3
    int cslot = (kq ^ (lr & 3)) << 4;
    int offk0 = ((lr >> 2) & 1) << 6;
    int offk1 = 64 - offk0;
    int aRd = (wr * 128 + lr) * 128 + cslot;
    int bRd = (wc * 64 + lr) * 128 + cslot;

#define RDA(D2, h, m, ks) (*(const bf16x8*)(lds + (D2)*32768 + aRd +          \
        (h)*8192 + (m)*2048 + ((ks) ? offk1 : offk0)))
#define RDB(D2, c, n, ks) (*(const bf16x8*)(lds + 65536 + (D2)*32768 + bRd +  \
        (c)*4096 + (n)*2048 + ((ks) ? offk1 : offk0)))

    f32x4 acc[8][4] = {};
    bf16x8 a[4][2], b0[2][2], b1[2][2];

#define FENCE asm volatile("" ::: "memory")
#define WAIT_LGKM asm volatile("s_waitcnt lgkmcnt(0)" ::: "memory")

#define KTILE(kt, D, S01, S23, VM) do {                                       \
    /* -------- P0: quadrant (h=0,c=0); opening reads post-barrier ------- */ \
    __builtin_amdgcn_s_barrier();                                             \
    _Pragma("unroll") for (int m = 0; m < 4; ++m) {                           \
        a[m][0] = RDA(D, 0, m, 0); a[m][1] = RDA(D, 0, m, 1); }               \
    _Pragma("unroll") for (int n = 0; n < 2; ++n) {                           \
        b0[n][0] = RDB(D, 0, n, 0); b0[n][1] = RDB(D, 0, n, 1); }             \
    WAIT_LGKM;                                                                \
    __builtin_amdgcn_s_setprio(1);                                            \
    _Pragma("unroll") for (int m = 0; m < 4; ++m)                             \
    _Pragma("unroll") for (int n = 0; n < 2; ++n)                             \
    _Pragma("unroll") for (int ks = 0; ks < 2; ++ks)                          \
        acc[m][n] = __builtin_amdgcn_mfma_f32_16x16x32_bf16(                  \
            a[m][ks], b0[n][ks], acc[m][n], 0, 0, 0);                         \
    __builtin_amdgcn_s_setprio(0);                                            \
    /* P0 tail: reads for P1; stage B1(k+1) */                                \
    _Pragma("unroll") for (int n = 0; n < 2; ++n) {                           \
        b1[n][0] = RDB(D, 1, n, 0); b1[n][1] = RDB(D, 1, n, 1); }             \
    if (S01) STAGE_B((kt) + 1, 1, (D) ^ 1);                                   \
    FENCE;                                                                    \
    /* -------- P1: quadrant (h=0,c=1) ----------------------------------- */ \
    __builtin_amdgcn_s_barrier();                                             \
    WAIT_LGKM;                                                                \
    __builtin_amdgcn_s_setprio(1);                                            \
    _Pragma("unroll") for (int m = 0; m < 4; ++m)                             \
    _Pragma("unroll") for (int n = 0; n < 2; ++n)                             \
    _Pragma("unroll") for (int ks = 0; ks < 2; ++ks)                          \
        acc[m][2 + n] = __builtin_amdgcn_mfma_f32_16x16x32_bf16(              \
            a[m][ks], b1[n][ks], acc[m][2 + n], 0, 0, 0);                     \
    __builtin_amdgcn_s_setprio(0);                                            \
    /* P1 tail: reads for P2 (A h=1, overwrites a[]); stage A1(k+1) */        \
    _Pragma("unroll") for (int m = 0; m < 4; ++m) {                           \
        a[m][0] = RDA(D, 1, m, 0); a[m][1] = RDA(D, 1, m, 1); }               \
    if (S01) STAGE_A((kt) + 1, 1, (D) ^ 1);                                   \
    FENCE;                                                                    \
    /* -------- P2: quadrant (h=1,c=0) ----------------------------------- */ \
    __builtin_amdgcn_s_barrier();                                             \
    WAIT_LGKM;                                                                \
    __builtin_amdgcn_s_setprio(1);                                            \
    _Pragma("unroll") for (int m = 0; m < 4; ++m)                             \
    _Pragma("unroll") for (int n = 0; n < 2; ++n)                             \
    _Pragma("unroll") for (int ks = 0; ks < 2; ++ks)                          \
        acc[4 + m][n] = __builtin_amdgcn_mfma_f32_16x16x32_bf16(              \
            a[m][ks], b0[n][ks], acc[4 + m][n], 0, 0, 0);                     \
    __builtin_amdgcn_s_setprio(0);                                            \
    /* P2 tail: stage B0(k+2) */                                              \
    if (S23) STAGE_B((kt) + 2, 0, D);                                         \
    FENCE;                                                                    \
    /* -------- P3: quadrant (h=1,c=1); operands already in regs --------- */ \
    __builtin_amdgcn_s_barrier();                                             \
    __builtin_amdgcn_s_setprio(1);                                            \
    _Pragma("unroll") for (int m = 0; m < 4; ++m)                             \
    _Pragma("unroll") for (int n = 0; n < 2; ++n)                             \
    _Pragma("unroll") for (int ks = 0; ks < 2; ++ks)                          \
        acc[4 + m][2 + n] = __builtin_amdgcn_mfma_f32_16x16x32_bf16(          \
            a[m][ks], b1[n][ks], acc[4 + m][2 + n], 0, 0, 0);                 \
    __builtin_amdgcn_s_setprio(0);                                            \
    /* P3 tail: stage A0(k+2); counted vmcnt */                               \
    if (S23) STAGE_A((kt) + 2, 0, D);                                         \
    if ((VM) == 4) asm volatile("s_waitcnt vmcnt(4)" ::: "memory");           \
    else if ((VM) == 0) asm volatile("s_waitcnt vmcnt(0)" ::: "memory");      \
    FENCE;                                                                    \
    } while (0)

    // prologue: tile 0 fully + h0 of tile 1 (12 loads/thread);
    // vmcnt(4) leaves exactly B0(1), A0(1) pending.
    STAGE_B(0, 0, 0); STAGE_A(0, 0, 0);
    STAGE_B(0, 1, 0); STAGE_A(0, 1, 0);
    STAGE_B(1, 0, 1); STAGE_A(1, 0, 1);
    asm volatile("s_waitcnt vmcnt(4)" ::: "memory");

    for (int t = 0; t < (NT - 2) / 2; ++t) {   // k = 0 .. 61
        KTILE(2 * t, 0, 1, 1, 4);
        KTILE(2 * t + 1, 1, 1, 1, 4);
    }
    KTILE(NT - 2, 0, 1, 0, 0);                 // k = 62: stage h1(63), drain
    KTILE(NT - 1, 1, 0, 0, -1);                // k = 63: compute only

    // epilogue: C/D layout col=lane&15, row=(lane>>4)*4+r
    int row0 = by * BM + wr * 128 + (lane >> 4) * 4;
    int col0 = bx * BN + wc * 64 + lr;
#pragma unroll
    for (int c = 0; c < 2; ++c)
#pragma unroll
    for (int n = 0; n < 2; ++n) {
        int col = col0 + c * 32 + n * 16;
        float bv = bias[col];
#pragma unroll
        for (int h = 0; h < 2; ++h)
#pragma unroll
        for (int m = 0; m < 4; ++m)
#pragma unroll
        for (int r = 0; r < 4; ++r) {
            int row = row0 + h * 64 + m * 16 + r;
            C[(size_t)row * OUT_F + col] = acc[h * 4 + m][c * 2 + n][r] + bv;
        }
    }
#undef KTILE
#undef FENCE
#undef WAIT_LGKM
#undef RDA
#undef RDB
#undef STAGE_A
#undef STAGE_B
}

// ---------------------------------------------------------------------------
extern "C" void kernel_launch(void* const* d_in, const int* in_sizes, int n_in,
                              void* d_out, int out_size, void* d_ws, size_t ws_size,
                              hipStream_t stream) {
    const float* x      = (const float*)d_in[0];
    const int*   Wq     = (const int*)d_in[1];
    const int*   sq     = (const int*)d_in[2];
    const int*   zq     = (const int*)d_in[3];
    const float* ss     = (const float*)d_in[4];
    const float* zs     = (const float*)d_in[5];
    const float* sz     = (const float*)d_in[6];
    const float* zz     = (const float*)d_in[7];
    const float* bias   = (const float*)d_in[8];
    float* out = (float*)d_out;

    unsigned short* xb = (unsigned short*)d_ws;
    unsigned short* Wb = (unsigned short*)((char*)d_ws + (size_t)M_ROWS * IN_F * 2);

    dequant_w_kernel<<<8192, 256, 0, stream>>>(Wq, sq, zq, ss, zs, sz, zz, Wb);
    convert_x_kernel<<<16384, 256, 0, stream>>>(x, xb);
    gemm_bf16_kernel<<<512, 512, 0, stream>>>(xb, Wb, bias, out);
}